// Round 4
// baseline (12365.977 us; speedup 1.0000x reference)
//
#include <hip/hip_runtime.h>
#include <hip/hip_fp16.h>
#include <math.h>

#define BATCH 32
#define TLEN  1024
#define DIN   128
#define HID   512
#define NCLS  10
#define NB    2                 // batches per WG
#define NGRP  (BATCH/NB)        // 16 groups
#define NSL   8                 // slice WGs per group per layer (64 cols each)
#define RING  32                // ring depth (slots)
#define SENTV 0xFFFFFFFFu
#define SENT64 0xFFFFFFFFFFFFFFFFull
#define POLL_CAP (1u<<17)

typedef _Float16 hf2 __attribute__((ext_vector_type(2)));

__device__ __forceinline__ unsigned aload(const unsigned* p) {
  return __hip_atomic_load(p, __ATOMIC_RELAXED, __HIP_MEMORY_SCOPE_AGENT);
}
__device__ __forceinline__ void astore(unsigned* p, unsigned v) {
  __hip_atomic_store(p, v, __ATOMIC_RELAXED, __HIP_MEMORY_SCOPE_AGENT);
}
__device__ __forceinline__ unsigned long long aload64(const unsigned long long* p) {
  return __hip_atomic_load(p, __ATOMIC_RELAXED, __HIP_MEMORY_SCOPE_AGENT);
}
__device__ __forceinline__ void astore64(unsigned long long* p, unsigned long long v) {
  __hip_atomic_store(p, v, __ATOMIC_RELAXED, __HIP_MEMORY_SCOPE_AGENT);
}
__device__ __forceinline__ int aloadi(const int* p) {
  return __hip_atomic_load(p, __ATOMIC_RELAXED, __HIP_MEMORY_SCOPE_AGENT);
}
__device__ __forceinline__ void astorei(int* p, int v) {
  __hip_atomic_store(p, v, __ATOMIC_RELAXED, __HIP_MEMORY_SCOPE_AGENT);
}

__device__ __forceinline__ float fdot2u(unsigned a, unsigned b, float c) {
#if __has_builtin(__builtin_amdgcn_fdot2)
  return __builtin_amdgcn_fdot2(__builtin_bit_cast(hf2, a),
                                __builtin_bit_cast(hf2, b), c, false);
#else
  hf2 av = __builtin_bit_cast(hf2, a), bv = __builtin_bit_cast(hf2, b);
  return c + (float)av[0] * (float)bv[0] + (float)av[1] * (float)bv[1];
#endif
}

__device__ __forceinline__ unsigned packh2(float lo, float hi) {
  __half2 h = __floats2half2_rn(lo, hi);
  return __builtin_bit_cast(unsigned, h);
}

// ---------- xw1[t,b,:] = x[b,t,:] @ Wx1 + b1, packed f16 pairs, all T ----------
__global__ __launch_bounds__(256) void k_xw1(
    const float* __restrict__ x, const float* __restrict__ Wx1,
    const float* __restrict__ b1, unsigned* __restrict__ xw1)   // [T*B][256] words
{
  __shared__ float xst[DIN * 4];
  const int tid  = threadIdx.x;
  const int row0 = blockIdx.x * 4;            // row = t*32 + b
  for (int idx = tid; idx < 4 * DIN; idx += 256) {
    int r = idx >> 7, d = idx & (DIN - 1);
    int row = row0 + r;
    int t = row >> 5, b = row & 31;
    xst[d * 4 + r] = x[((size_t)b * TLEN + t) * DIN + d];
  }
  __syncthreads();
  float acc[4][2];
#pragma unroll
  for (int r = 0; r < 4; ++r) { acc[r][0] = 0.f; acc[r][1] = 0.f; }
  const int j0 = 2 * tid, j1 = 2 * tid + 1;
  for (int d = 0; d < DIN; ++d) {
    float w0 = Wx1[(size_t)d * HID + j0];
    float w1 = Wx1[(size_t)d * HID + j1];
    float4 xv = *reinterpret_cast<const float4*>(&xst[d * 4]);
    acc[0][0] += xv.x * w0; acc[0][1] += xv.x * w1;
    acc[1][0] += xv.y * w0; acc[1][1] += xv.y * w1;
    acc[2][0] += xv.z * w0; acc[2][1] += xv.z * w1;
    acc[3][0] += xv.w * w0; acc[3][1] += xv.w * w1;
  }
  float bb0 = b1[j0], bb1 = b1[j1];
#pragma unroll
  for (int r = 0; r < 4; ++r)
    xw1[(size_t)(row0 + r) * 256 + tid] = packh2(acc[r][0] + bb0, acc[r][1] + bb1);
}

// ---------- persistent pipelined 2-layer recurrence ----------
// grid 256 x 512. XCD-colocated mapping: all 16 WGs of a batch-group share
// wgid%8 (same XCD under round-robin dispatch). wgid = (g&7) + 8*(sl + 8*L +
// 16*(g>>3)). Within a wave: lane = q*16+lo, q = K-quarter; output o = w*16+lo.
// One barrier/step; parity-double-buffered h_s; sentinel-flagged rings;
// early-probe/late-spin; bank-conflict-free rotated LDS reads.
__global__ __launch_bounds__(512) void k_rnn(
    const unsigned* __restrict__ xw1,     // [T*B][256]
    const float* __restrict__ Wh1,
    const float* __restrict__ Wx2, const float* __restrict__ Wh2,
    const float* __restrict__ b2,
    unsigned* __restrict__ ring1,         // [RING][B][256]: L1 h (peers t-1, L2 t)
    unsigned* __restrict__ ringC,         // [RING][B][256]: L2 self
    int* __restrict__ prog2,              // [NGRP][NSL] L2 progress
    float* __restrict__ h2fin)            // [B][H]
{
  const int tid  = threadIdx.x;
  const int wgid = blockIdx.x;
  const int xcd   = wgid & 7;
  const int mm    = wgid >> 3;
  const int sl    = mm & 7;
  const int layer = (mm >> 3) & 1;
  const int g     = ((mm >> 4) << 3) | xcd;
  const int b0 = g * NB;
  const int c0 = sl * 64;
  const int w  = tid >> 6, l = tid & 63;
  const int q  = l >> 4;                 // K-quarter
  const int lo = l & 15;
  const int o  = w * 16 + lo;            // 0..127
  const int obb = o >> 6, oj = o & 63;
  const int ocol = c0 + oj;

  const int pu = tid & 127;              // u64 poll index

  __shared__ __align__(16) unsigned h_s[2][NB][512];  // [parity][batch][word]

  if (layer == 0) {
    // ================= LAYER 1 (K=512) =================
    const int pb = (tid >> 7) & 1;       // poll batch (tid<256)
    unsigned wreg[64];
    {
      const int k0 = q * 128;
#pragma unroll
      for (int i = 0; i < 64; ++i) {
        float a = Wh1[(size_t)(k0 + 2 * i) * HID + ocol];
        float b = Wh1[(size_t)(k0 + 2 * i + 1) * HID + ocol];
        wreg[i] = packh2(a, b);
      }
    }
    int cached = -1;
    for (int t = 0; t < TLEN; ++t) {
      const int p = t & 1;
      // --- early probe: first vmem op of the step ---
      unsigned long long v64 = 0;
      const unsigned long long* pp = nullptr;
      if (tid < 256 && t > 0) {
        pp = (const unsigned long long*)
             &ring1[((size_t)((t - 1) & (RING - 1)) * BATCH + b0 + pb) * 256 + 2 * pu];
        v64 = aload64(pp);
      }
      // xw prefetch (q0 lanes use it in finalize)
      unsigned xww = 0;
      if (q == 0)
        xww = xw1[((size_t)t * BATCH + b0 + obb) * 256 + (ocol >> 1)];
      // wave 0: throttle L2 lag, then reset slot t+1 (holds step t-31)
      if (w == 0) {
        const int need = t - (RING - 8);
        if (cached < need) {
          unsigned it = 0;
          for (;;) {
            int pr = (l < NSL) ? aloadi(&prog2[g * NSL + l]) : 0x7fffffff;
#pragma unroll
            for (int d = 1; d < NSL; d <<= 1) pr = min(pr, __shfl_xor(pr, d));
            pr = __shfl(pr, 0);
            cached = pr;
            if (cached >= need || ++it >= POLL_CAP) break;
          }
        }
        if (l < 32) {
          int rb = l >> 4, jj = l & 15;
          astore64((unsigned long long*)
                   &ring1[((size_t)((t + 1) & (RING - 1)) * BATCH + b0 + rb) * 256
                          + (c0 >> 1) + 2 * jj], SENT64);
        }
      }
      // --- late spin + h_s publish ---
      if (tid < 256) {
        if (t > 0) {
          unsigned v0 = (unsigned)v64, v1 = (unsigned)(v64 >> 32);
          if (v0 == SENTV || v1 == SENTV) {
            unsigned it = 0;
            do {
              unsigned long long nv = aload64(pp);
              v0 = (unsigned)nv; v1 = (unsigned)(nv >> 32);
            } while ((v0 == SENTV || v1 == SENTV) && ++it < POLL_CAP);
            if (v0 == SENTV) v0 = 0;
            if (v1 == SENTV) v1 = 0;
            v64 = ((unsigned long long)v1 << 32) | v0;
          }
        }
        *(unsigned long long*)&h_s[p][pb][2 * pu] = v64;
      }
      __syncthreads();   // h_s[p] ready; wave-0 resets drained (vmcnt0+barrier)
      float acc = 0.f;
      const unsigned* hp = &h_s[p][obb][q * 64];
#pragma unroll
      for (int i = 0; i < 16; ++i) {
        const int r = 4 * ((i + q) & 15);   // rotated: quarters hit disjoint banks
        uint4 hv = *reinterpret_cast<const uint4*>(&hp[r]);
        acc = fdot2u(hv.x, wreg[r + 0], acc);
        acc = fdot2u(hv.y, wreg[r + 1], acc);
        acc = fdot2u(hv.z, wreg[r + 2], acc);
        acc = fdot2u(hv.w, wreg[r + 3], acc);
      }
      acc += __shfl_xor(acc, 16);
      acc += __shfl_xor(acc, 32);
      if (q == 0) {
        hf2 xv = __builtin_bit_cast(hf2, xww);
        float z = (float)xv[oj & 1] + acc;
        float h = tanhf(z);
        float hn = __shfl_down(h, 1);
        if (!(lo & 1))
          astore(&ring1[((size_t)(t & (RING - 1)) * BATCH + b0 + obb) * 256 + (ocol >> 1)],
                 packh2(h, hn));
      }
    }
  } else {
    // ================= LAYER 2 (K=1024: [h1(t); h2(t-1)] @ [Wx2;Wh2]) =========
    const int set = tid >> 7;             // 0,1: ring1 b0/b1; 2,3: ringC b0/b1
    unsigned wreg[128];
    {
      const int k0 = q * 256;
#pragma unroll
      for (int i = 0; i < 128; ++i) {
        int k = k0 + 2 * i;
        float a, b;
        if (k < HID) {
          a = Wx2[(size_t)k * HID + ocol];
          b = Wx2[(size_t)(k + 1) * HID + ocol];
        } else {
          a = Wh2[(size_t)(k - HID) * HID + ocol];
          b = Wh2[(size_t)(k - HID + 1) * HID + ocol];
        }
        wreg[i] = packh2(a, b);
      }
    }
    float b2v = (q == 0) ? b2[ocol] : 0.f;
    for (int t = 0; t < TLEN; ++t) {
      const int p = t & 1;
      // --- early probe ---
      unsigned long long v64 = 0;
      const unsigned long long* pp = nullptr;
      if (set < 2) {
        pp = (const unsigned long long*)
             &ring1[((size_t)(t & (RING - 1)) * BATCH + b0 + set) * 256 + 2 * pu];
        v64 = aload64(pp);
      } else if (t > 0) {
        pp = (const unsigned long long*)
             &ringC[((size_t)((t - 1) & (RING - 1)) * BATCH + b0 + (set - 2)) * 256 + 2 * pu];
        v64 = aload64(pp);
      }
      // wave 0: reset ringC slot t+1
      if (w == 0 && l < 32) {
        int rb = l >> 4, jj = l & 15;
        astore64((unsigned long long*)
                 &ringC[((size_t)((t + 1) & (RING - 1)) * BATCH + b0 + rb) * 256
                        + (c0 >> 1) + 2 * jj], SENT64);
      }
      // --- late spin + h_s publish ---
      if (pp) {
        unsigned v0 = (unsigned)v64, v1 = (unsigned)(v64 >> 32);
        if (v0 == SENTV || v1 == SENTV) {
          unsigned it = 0;
          do {
            unsigned long long nv = aload64(pp);
            v0 = (unsigned)nv; v1 = (unsigned)(nv >> 32);
          } while ((v0 == SENTV || v1 == SENTV) && ++it < POLL_CAP);
          if (v0 == SENTV) v0 = 0;
          if (v1 == SENTV) v1 = 0;
          v64 = ((unsigned long long)v1 << 32) | v0;
        }
      }
      {
        const int bb = set & 1;
        const int base = (set >> 1) * 256;   // h1 at 0, h2 at 256
        *(unsigned long long*)&h_s[p][bb][base + 2 * pu] = v64;
      }
      __syncthreads();
      if (tid == 0 && (t & 3) == 0) astorei(&prog2[g * NSL + sl], t);
      float acc = 0.f;
      const unsigned* hp = &h_s[p][obb][q * 128];
#pragma unroll
      for (int i = 0; i < 32; ++i) {
        const int r = 4 * ((i + q) & 31);
        uint4 hv = *reinterpret_cast<const uint4*>(&hp[r]);
        acc = fdot2u(hv.x, wreg[r + 0], acc);
        acc = fdot2u(hv.y, wreg[r + 1], acc);
        acc = fdot2u(hv.z, wreg[r + 2], acc);
        acc = fdot2u(hv.w, wreg[r + 3], acc);
      }
      acc += __shfl_xor(acc, 16);
      acc += __shfl_xor(acc, 32);
      if (q == 0) {
        float z = b2v + acc;
        float h = tanhf(z);
        if (t == TLEN - 1) h2fin[(size_t)(b0 + obb) * HID + ocol] = h;
        float hn = __shfl_down(h, 1);
        if (!(lo & 1))
          astore(&ringC[((size_t)(t & (RING - 1)) * BATCH + b0 + obb) * 256 + (ocol >> 1)],
                 packh2(h, hn));
      }
    }
  }
}

// ---------- softmax(h2 @ Wo + bo) ----------
__global__ __launch_bounds__(640) void k_head(
    const float* __restrict__ h2, const float* __restrict__ Wo,
    const float* __restrict__ bo, float* __restrict__ out)
{
  __shared__ float lg[16];
  const int b = blockIdx.x;
  const int c = threadIdx.x >> 6;   // wave per class
  const int l = threadIdx.x & 63;
  float p = 0.f;
#pragma unroll
  for (int i = 0; i < 8; ++i) {
    int k = l + 64 * i;
    p += h2[(size_t)b * HID + k] * Wo[(size_t)k * NCLS + c];
  }
  for (int off = 32; off; off >>= 1) p += __shfl_down(p, off);
  if (l == 0) lg[c] = p + bo[c];
  __syncthreads();
  if (threadIdx.x == 0) {
    float m = lg[0];
    for (int i = 1; i < NCLS; ++i) m = fmaxf(m, lg[i]);
    float e[NCLS];
    float s = 0.f;
    for (int i = 0; i < NCLS; ++i) { e[i] = expf(lg[i] - m); s += e[i]; }
    for (int i = 0; i < NCLS; ++i) out[(size_t)b * NCLS + i] = e[i] / s;
  }
}

extern "C" void kernel_launch(void* const* d_in, const int* in_sizes, int n_in,
                              void* d_out, int out_size, void* d_ws, size_t ws_size,
                              hipStream_t stream)
{
  (void)in_sizes; (void)n_in; (void)out_size; (void)ws_size;
  const float* x   = (const float*)d_in[0];
  const float* Wx1 = (const float*)d_in[1];
  const float* Wh1 = (const float*)d_in[2];
  const float* b1  = (const float*)d_in[3];
  const float* Wx2 = (const float*)d_in[4];
  const float* Wh2 = (const float*)d_in[5];
  const float* b2  = (const float*)d_in[6];
  const float* Wo  = (const float*)d_in[7];
  const float* bo  = (const float*)d_in[8];
  float* out = (float*)d_out;

  char* ws = (char*)d_ws;
  size_t o = 0;
  unsigned* xw1 = (unsigned*)(ws + o); o += (size_t)TLEN * BATCH * 256 * 4;  // 32MB
  const size_t ringBytes = (size_t)RING * BATCH * 256 * 4;                   // 1MB
  unsigned* ring1 = (unsigned*)(ws + o); o += ringBytes;
  unsigned* ringC = (unsigned*)(ws + o); o += ringBytes;
  int* prog2 = (int*)(ws + o); o += 1024;
  float* h2fin = (float*)(ws + o); o += (size_t)BATCH * HID * 4;

  hipMemsetAsync(ring1, 0xFF, 2 * ringBytes, stream);   // ring1, ringC contiguous
  hipMemsetAsync(prog2, 0xFF, NGRP * NSL * 4, stream);

  k_xw1<<<TLEN * BATCH / 4, 256, 0, stream>>>(x, Wx1, b1, xw1);
  k_rnn<<<256, 512, 0, stream>>>(xw1, Wh1, Wx2, Wh2, b2,
                                 ring1, ringC, prog2, h2fin);
  k_head<<<BATCH, 640, 0, stream>>>(h2fin, Wo, bo, out);
}

// Round 5
// 1983.016 us; speedup vs baseline: 6.2359x; 6.2359x over previous
//
#include <hip/hip_runtime.h>
#include <hip/hip_fp16.h>
#include <math.h>

#define BATCH 32
#define TLEN  1024
#define DIN   128
#define HID   512
#define NCLS  10
#define NB    2                 // batches per WG
#define NGRP  (BATCH/NB)        // 16 groups
#define NSL   8                 // slice WGs per group per layer (64 cols each)
#define RING  32                // ring depth (slots)
#define SENTV 0xFFFFFFFFu
#define SENT64 0xFFFFFFFFFFFFFFFFull
#define POLL_CAP (1u<<17)

typedef _Float16 hf2 __attribute__((ext_vector_type(2)));

__device__ __forceinline__ unsigned aload(const unsigned* p) {
  return __hip_atomic_load(p, __ATOMIC_RELAXED, __HIP_MEMORY_SCOPE_AGENT);
}
__device__ __forceinline__ void astore(unsigned* p, unsigned v) {
  __hip_atomic_store(p, v, __ATOMIC_RELAXED, __HIP_MEMORY_SCOPE_AGENT);
}
__device__ __forceinline__ unsigned long long aload64(const unsigned long long* p) {
  return __hip_atomic_load(p, __ATOMIC_RELAXED, __HIP_MEMORY_SCOPE_AGENT);
}
__device__ __forceinline__ void astore64(unsigned long long* p, unsigned long long v) {
  __hip_atomic_store(p, v, __ATOMIC_RELAXED, __HIP_MEMORY_SCOPE_AGENT);
}
__device__ __forceinline__ int aloadi(const int* p) {
  return __hip_atomic_load(p, __ATOMIC_RELAXED, __HIP_MEMORY_SCOPE_AGENT);
}
__device__ __forceinline__ void astorei(int* p, int v) {
  __hip_atomic_store(p, v, __ATOMIC_RELAXED, __HIP_MEMORY_SCOPE_AGENT);
}

__device__ __forceinline__ float fdot2u(unsigned a, unsigned b, float c) {
#if __has_builtin(__builtin_amdgcn_fdot2)
  return __builtin_amdgcn_fdot2(__builtin_bit_cast(hf2, a),
                                __builtin_bit_cast(hf2, b), c, false);
#else
  hf2 av = __builtin_bit_cast(hf2, a), bv = __builtin_bit_cast(hf2, b);
  return c + (float)av[0] * (float)bv[0] + (float)av[1] * (float)bv[1];
#endif
}

__device__ __forceinline__ unsigned packh2(float lo, float hi) {
  __half2 h = __floats2half2_rn(lo, hi);
  return __builtin_bit_cast(unsigned, h);
}

// ---------- xw1[t,b,:] = x[b,t,:] @ Wx1 + b1, packed f16 pairs, all T ----------
__global__ __launch_bounds__(256) void k_xw1(
    const float* __restrict__ x, const float* __restrict__ Wx1,
    const float* __restrict__ b1, unsigned* __restrict__ xw1)   // [T*B][256] words
{
  __shared__ float xst[DIN * 4];
  const int tid  = threadIdx.x;
  const int row0 = blockIdx.x * 4;            // row = t*32 + b
  for (int idx = tid; idx < 4 * DIN; idx += 256) {
    int r = idx >> 7, d = idx & (DIN - 1);
    int row = row0 + r;
    int t = row >> 5, b = row & 31;
    xst[d * 4 + r] = x[((size_t)b * TLEN + t) * DIN + d];
  }
  __syncthreads();
  float acc[4][2];
#pragma unroll
  for (int r = 0; r < 4; ++r) { acc[r][0] = 0.f; acc[r][1] = 0.f; }
  const int j0 = 2 * tid, j1 = 2 * tid + 1;
  for (int d = 0; d < DIN; ++d) {
    float w0 = Wx1[(size_t)d * HID + j0];
    float w1 = Wx1[(size_t)d * HID + j1];
    float4 xv = *reinterpret_cast<const float4*>(&xst[d * 4]);
    acc[0][0] += xv.x * w0; acc[0][1] += xv.x * w1;
    acc[1][0] += xv.y * w0; acc[1][1] += xv.y * w1;
    acc[2][0] += xv.z * w0; acc[2][1] += xv.z * w1;
    acc[3][0] += xv.w * w0; acc[3][1] += xv.w * w1;
  }
  float bb0 = b1[j0], bb1 = b1[j1];
#pragma unroll
  for (int r = 0; r < 4; ++r)
    xw1[(size_t)(row0 + r) * 256 + tid] = packh2(acc[r][0] + bb0, acc[r][1] + bb1);
}

// ---------- persistent pipelined 2-layer recurrence ----------
// grid 256 x 512. XCD-colocated mapping: all 16 WGs of a batch-group share
// wgid%8 (same XCD under round-robin dispatch). Within a wave: lane = q*16+lo,
// q = K-quarter; output o = w*16+lo. One barrier/step; parity-double-buffered
// h_s; sentinel-flagged rings; early-probe/late-spin.
// Bank-conflict fix: LDS read offset rotated by quarter (runtime ds addr),
// weight-REGISTER order rotated identically at init (indices stay static!).
__global__ __launch_bounds__(512) void k_rnn(
    const unsigned* __restrict__ xw1,     // [T*B][256]
    const float* __restrict__ Wh1,
    const float* __restrict__ Wx2, const float* __restrict__ Wh2,
    const float* __restrict__ b2,
    unsigned* __restrict__ ring1,         // [RING][B][256]: L1 h (peers t-1, L2 t)
    unsigned* __restrict__ ringC,         // [RING][B][256]: L2 self
    int* __restrict__ prog2,              // [NGRP][NSL] L2 progress
    float* __restrict__ h2fin)            // [B][H]
{
  const int tid  = threadIdx.x;
  const int wgid = blockIdx.x;
  const int xcd   = wgid & 7;
  const int mm    = wgid >> 3;
  const int sl    = mm & 7;
  const int layer = (mm >> 3) & 1;
  const int g     = ((mm >> 4) << 3) | xcd;
  const int b0 = g * NB;
  const int c0 = sl * 64;
  const int w  = tid >> 6, l = tid & 63;
  const int q  = l >> 4;                 // K-quarter
  const int lo = l & 15;
  const int o  = w * 16 + lo;            // 0..127
  const int obb = o >> 6, oj = o & 63;
  const int ocol = c0 + oj;

  const int pu = tid & 127;              // u64 poll index

  __shared__ __align__(16) unsigned h_s[2][NB][512];  // [parity][batch][word]

  if (layer == 0) {
    // ================= LAYER 1 (K=512) =================
    const int pb = (tid >> 7) & 1;       // poll batch (tid<256)
    unsigned wreg[64];
    {
      const int k0 = q * 128;            // k base for this quarter
#pragma unroll
      for (int i = 0; i < 16; ++i) {
        const int rr = 4 * ((i + q) & 15);   // rotated word offset within quarter
#pragma unroll
        for (int j = 0; j < 4; ++j) {
          const int k = k0 + 2 * (rr + j);
          wreg[4 * i + j] = packh2(Wh1[(size_t)k * HID + ocol],
                                   Wh1[(size_t)(k + 1) * HID + ocol]);
        }
      }
    }
    int cached = -1;
    for (int t = 0; t < TLEN; ++t) {
      const int p = t & 1;
      // --- early probe: first vmem op of the step ---
      unsigned long long v64 = 0;
      const unsigned long long* pp = nullptr;
      if (tid < 256 && t > 0) {
        pp = (const unsigned long long*)
             &ring1[((size_t)((t - 1) & (RING - 1)) * BATCH + b0 + pb) * 256 + 2 * pu];
        v64 = aload64(pp);
      }
      // xw prefetch (q0 lanes use it in finalize)
      unsigned xww = 0;
      if (q == 0)
        xww = xw1[((size_t)t * BATCH + b0 + obb) * 256 + (ocol >> 1)];
      // wave 0: throttle L2 lag, then reset slot t+1 (holds step t-31)
      if (w == 0) {
        const int need = t - (RING - 6);
        if (cached < need) {
          unsigned it = 0;
          for (;;) {
            int pr = (l < NSL) ? aloadi(&prog2[g * NSL + l]) : 0x7fffffff;
#pragma unroll
            for (int d = 1; d < NSL; d <<= 1) pr = min(pr, __shfl_xor(pr, d));
            pr = __shfl(pr, 0);
            cached = pr;
            if (cached >= need || ++it >= POLL_CAP) break;
          }
        }
        if (l < 32) {
          int rb = l >> 4, jj = l & 15;
          astore64((unsigned long long*)
                   &ring1[((size_t)((t + 1) & (RING - 1)) * BATCH + b0 + rb) * 256
                          + (c0 >> 1) + 2 * jj], SENT64);
        }
      }
      // --- late spin + h_s publish ---
      if (tid < 256) {
        if (t > 0) {
          unsigned v0 = (unsigned)v64, v1 = (unsigned)(v64 >> 32);
          if (v0 == SENTV || v1 == SENTV) {
            unsigned it = 0;
            do {
              unsigned long long nv = aload64(pp);
              v0 = (unsigned)nv; v1 = (unsigned)(nv >> 32);
            } while ((v0 == SENTV || v1 == SENTV) && ++it < POLL_CAP);
            if (v0 == SENTV) v0 = 0;
            if (v1 == SENTV) v1 = 0;
            v64 = ((unsigned long long)v1 << 32) | v0;
          }
        }
        *(unsigned long long*)&h_s[p][pb][2 * pu] = v64;
      }
      __syncthreads();   // h_s[p] ready; wave-0 resets drained (vmcnt0+barrier)
      float acc = 0.f;
      const unsigned* hp = &h_s[p][obb][q * 64];
#pragma unroll
      for (int i = 0; i < 16; ++i) {
        const int rr = 4 * ((i + q) & 15);   // quarters hit disjoint bank quads
        uint4 hv = *reinterpret_cast<const uint4*>(&hp[rr]);
        acc = fdot2u(hv.x, wreg[4 * i + 0], acc);
        acc = fdot2u(hv.y, wreg[4 * i + 1], acc);
        acc = fdot2u(hv.z, wreg[4 * i + 2], acc);
        acc = fdot2u(hv.w, wreg[4 * i + 3], acc);
      }
      acc += __shfl_xor(acc, 16);
      acc += __shfl_xor(acc, 32);
      if (q == 0) {
        hf2 xv = __builtin_bit_cast(hf2, xww);
        float z = (float)xv[oj & 1] + acc;
        float h = tanhf(z);
        float hn = __shfl_down(h, 1);
        if (!(lo & 1))
          astore(&ring1[((size_t)(t & (RING - 1)) * BATCH + b0 + obb) * 256 + (ocol >> 1)],
                 packh2(h, hn));
      }
    }
  } else {
    // ================= LAYER 2 (K=1024: [h1(t); h2(t-1)] @ [Wx2;Wh2]) =========
    const int set = tid >> 7;             // 0,1: ring1 b0/b1; 2,3: ringC b0/b1
    unsigned wreg[128];
    {
      const int k0 = q * 256;
#pragma unroll
      for (int i = 0; i < 32; ++i) {
        const int rr = 4 * ((i + q) & 31);
#pragma unroll
        for (int j = 0; j < 4; ++j) {
          const int k = k0 + 2 * (rr + j);
          float a, b;
          if (k < HID) {
            a = Wx2[(size_t)k * HID + ocol];
            b = Wx2[(size_t)(k + 1) * HID + ocol];
          } else {
            a = Wh2[(size_t)(k - HID) * HID + ocol];
            b = Wh2[(size_t)(k - HID + 1) * HID + ocol];
          }
          wreg[4 * i + j] = packh2(a, b);
        }
      }
    }
    float b2v = (q == 0) ? b2[ocol] : 0.f;
    for (int t = 0; t < TLEN; ++t) {
      const int p = t & 1;
      // --- early probe ---
      unsigned long long v64 = 0;
      const unsigned long long* pp = nullptr;
      if (set < 2) {
        pp = (const unsigned long long*)
             &ring1[((size_t)(t & (RING - 1)) * BATCH + b0 + set) * 256 + 2 * pu];
        v64 = aload64(pp);
      } else if (t > 0) {
        pp = (const unsigned long long*)
             &ringC[((size_t)((t - 1) & (RING - 1)) * BATCH + b0 + (set - 2)) * 256 + 2 * pu];
        v64 = aload64(pp);
      }
      // wave 0: reset ringC slot t+1
      if (w == 0 && l < 32) {
        int rb = l >> 4, jj = l & 15;
        astore64((unsigned long long*)
                 &ringC[((size_t)((t + 1) & (RING - 1)) * BATCH + b0 + rb) * 256
                        + (c0 >> 1) + 2 * jj], SENT64);
      }
      // --- late spin + h_s publish ---
      if (pp) {
        unsigned v0 = (unsigned)v64, v1 = (unsigned)(v64 >> 32);
        if (v0 == SENTV || v1 == SENTV) {
          unsigned it = 0;
          do {
            unsigned long long nv = aload64(pp);
            v0 = (unsigned)nv; v1 = (unsigned)(nv >> 32);
          } while ((v0 == SENTV || v1 == SENTV) && ++it < POLL_CAP);
          if (v0 == SENTV) v0 = 0;
          if (v1 == SENTV) v1 = 0;
          v64 = ((unsigned long long)v1 << 32) | v0;
        }
      }
      {
        const int bb = set & 1;
        const int base = (set >> 1) * 256;   // h1 at 0, h2 at 256
        *(unsigned long long*)&h_s[p][bb][base + 2 * pu] = v64;
      }
      __syncthreads();
      if (tid == 0) astorei(&prog2[g * NSL + sl], t);   // consumed ring1 slot t
      float acc = 0.f;
      const unsigned* hp = &h_s[p][obb][q * 128];
#pragma unroll
      for (int i = 0; i < 32; ++i) {
        const int rr = 4 * ((i + q) & 31);
        uint4 hv = *reinterpret_cast<const uint4*>(&hp[rr]);
        acc = fdot2u(hv.x, wreg[4 * i + 0], acc);
        acc = fdot2u(hv.y, wreg[4 * i + 1], acc);
        acc = fdot2u(hv.z, wreg[4 * i + 2], acc);
        acc = fdot2u(hv.w, wreg[4 * i + 3], acc);
      }
      acc += __shfl_xor(acc, 16);
      acc += __shfl_xor(acc, 32);
      if (q == 0) {
        float z = b2v + acc;
        float h = tanhf(z);
        if (t == TLEN - 1) h2fin[(size_t)(b0 + obb) * HID + ocol] = h;
        float hn = __shfl_down(h, 1);
        if (!(lo & 1))
          astore(&ringC[((size_t)(t & (RING - 1)) * BATCH + b0 + obb) * 256 + (ocol >> 1)],
                 packh2(h, hn));
      }
    }
  }
}

// ---------- softmax(h2 @ Wo + bo) ----------
__global__ __launch_bounds__(640) void k_head(
    const float* __restrict__ h2, const float* __restrict__ Wo,
    const float* __restrict__ bo, float* __restrict__ out)
{
  __shared__ float lg[16];
  const int b = blockIdx.x;
  const int c = threadIdx.x >> 6;   // wave per class
  const int l = threadIdx.x & 63;
  float p = 0.f;
#pragma unroll
  for (int i = 0; i < 8; ++i) {
    int k = l + 64 * i;
    p += h2[(size_t)b * HID + k] * Wo[(size_t)k * NCLS + c];
  }
  for (int off = 32; off; off >>= 1) p += __shfl_down(p, off);
  if (l == 0) lg[c] = p + bo[c];
  __syncthreads();
  if (threadIdx.x == 0) {
    float m = lg[0];
    for (int i = 1; i < NCLS; ++i) m = fmaxf(m, lg[i]);
    float e[NCLS];
    float s = 0.f;
    for (int i = 0; i < NCLS; ++i) { e[i] = expf(lg[i] - m); s += e[i]; }
    for (int i = 0; i < NCLS; ++i) out[(size_t)b * NCLS + i] = e[i] / s;
  }
}

extern "C" void kernel_launch(void* const* d_in, const int* in_sizes, int n_in,
                              void* d_out, int out_size, void* d_ws, size_t ws_size,
                              hipStream_t stream)
{
  (void)in_sizes; (void)n_in; (void)out_size; (void)ws_size;
  const float* x   = (const float*)d_in[0];
  const float* Wx1 = (const float*)d_in[1];
  const float* Wh1 = (const float*)d_in[2];
  const float* b1  = (const float*)d_in[3];
  const float* Wx2 = (const float*)d_in[4];
  const float* Wh2 = (const float*)d_in[5];
  const float* b2  = (const float*)d_in[6];
  const float* Wo  = (const float*)d_in[7];
  const float* bo  = (const float*)d_in[8];
  float* out = (float*)d_out;

  char* ws = (char*)d_ws;
  size_t o = 0;
  unsigned* xw1 = (unsigned*)(ws + o); o += (size_t)TLEN * BATCH * 256 * 4;  // 32MB
  const size_t ringBytes = (size_t)RING * BATCH * 256 * 4;                   // 1MB
  unsigned* ring1 = (unsigned*)(ws + o); o += ringBytes;
  unsigned* ringC = (unsigned*)(ws + o); o += ringBytes;
  int* prog2 = (int*)(ws + o); o += 1024;
  float* h2fin = (float*)(ws + o); o += (size_t)BATCH * HID * 4;

  hipMemsetAsync(ring1, 0xFF, 2 * ringBytes, stream);   // ring1, ringC contiguous
  hipMemsetAsync(prog2, 0xFF, NGRP * NSL * 4, stream);

  k_xw1<<<TLEN * BATCH / 4, 256, 0, stream>>>(x, Wx1, b1, xw1);
  k_rnn<<<256, 512, 0, stream>>>(xw1, Wh1, Wx2, Wh2, b2,
                                 ring1, ringC, prog2, h2fin);
  k_head<<<BATCH, 640, 0, stream>>>(h2fin, Wo, bo, out);
}